// Round 14
// baseline (566.668 us; speedup 1.0000x reference)
//
#include <hip/hip_runtime.h>

typedef __attribute__((ext_vector_type(8))) short bf16x8;
typedef __attribute__((ext_vector_type(4))) float f32x4;

// ---- bf16 (as ushort) helpers ----
__device__ __forceinline__ float b2f(unsigned short u) {
    return __uint_as_float(((unsigned int)u) << 16);
}
__device__ __forceinline__ unsigned short f2b(float f) {
    unsigned int u = __float_as_uint(f);
    unsigned int r = (u + 0x7FFFu + ((u >> 16) & 1u)) >> 16;   // RNE
    return (unsigned short)r;
}

// ---------------------------------------------------------------------------
// One-shot prep: build all 4 bf16 V matrices + zero deg and sums.
// (round 14: merged 4 prep launches + 2 memsets into 1 dispatch)
// complex: V[2j]=[wr,-wi] interleaved, V[2j+1]=[wi,wr]  ([2J x 2K] bf16)
// real:    V[2j]=wr row, V[2j+1]=wi row                 ([2J x K]  bf16)
// ---------------------------------------------------------------------------
__device__ __forceinline__ void prep_cplx_elem(
    const float* Wr, const float* Wi, unsigned short* V, int K, int idx)
{
    int j = idx / K, kk = idx % K;
    float wr = Wr[idx], wi = Wi[idx];
    int Kr = 2 * K;
    unsigned short* r0 = V + (size_t)(2 * j) * Kr + 2 * kk;
    unsigned short* r1 = V + (size_t)(2 * j + 1) * Kr + 2 * kk;
    r0[0] = f2b(wr);  r0[1] = f2b(-wi);
    r1[0] = f2b(wi);  r1[1] = f2b(wr);
}

__global__ __launch_bounds__(256) void prep_all_kernel(
    const float* __restrict__ W0r, const float* __restrict__ W0i,
    const float* __restrict__ M0r, const float* __restrict__ M0i,
    const float* __restrict__ W1r, const float* __restrict__ W1i,
    const float* __restrict__ M1r, const float* __restrict__ M1i,
    unsigned short* __restrict__ V0, unsigned short* __restrict__ VM0,
    unsigned short* __restrict__ V1, unsigned short* __restrict__ VM1,
    int* __restrict__ deg, float* __restrict__ sums, int N)
{
    int idx = blockIdx.x * 256 + threadIdx.x;
    int total = gridDim.x * 256;
    for (int i = idx; i < N; i += total) deg[i] = 0;
    if (idx < 4096) sums[idx] = 0.f;

    if (idx < 16384) {                       // W0 real: J=128,K=128
        int j = idx >> 7, k = idx & 127;
        V0[(size_t)(2 * j) * 128 + k]     = f2b(W0r[idx]);
        V0[(size_t)(2 * j + 1) * 128 + k] = f2b(W0i[idx]);
    } else if (idx < 32768) {                // M0 cplx: J=128,K=128
        prep_cplx_elem(M0r, M0i, VM0, 128, idx - 16384);
    } else if (idx < 40960) {                // W1 cplx: J=64,K=128
        prep_cplx_elem(W1r, W1i, V1, 128, idx - 32768);
    } else if (idx < 45056) {                // M1 cplx: J=64,K=64
        prep_cplx_elem(M1r, M1i, VM1, 64, idx - 40960);
    }
}

// ---------------------------------------------------------------------------
// MFMA complex GEMM as real GEMM:  D[f][n] = sum_c V[f][c] * A[n][c]
// Round 14: 128 nodes per block, 512 threads (8 waves). Wave w covers node
// half ng=w&1 (4 node-tiles) x feature group fg=w>>1 (TILES/4 tiles) — same
// per-wave tile count and acc budget as round 13, half the blocks, 2x
// V-staging amortization, half the total barrier-drain events.
// Epilogues: MIX=false -> +bias, optional CRELU; MIX=true -> unitary mix.
// NOTE (round 10): do NOT fuse abs/graph-reduce here (straggler serialization).
// ---------------------------------------------------------------------------
template<int Kr, int TWOJ, bool REAL_IN, bool CRELU, bool MIX>
__global__ __launch_bounds__(512) void mfma_cgemm_kernel(
    const void* __restrict__ Xv,
    const unsigned short* __restrict__ Vg,
    const float* __restrict__ br, const float* __restrict__ bi,
    const float* __restrict__ trp, const float* __restrict__ tip,
    const unsigned short* __restrict__ Hin, const int* __restrict__ degp,
    unsigned short* __restrict__ Out, int nNodes)
{
    constexpr int TILES  = TWOJ / 16;
    constexpr int FT     = TILES / 4;   // feature tiles per wave
    constexpr int CHUNKS = Kr / 32;
    constexpr int VROW   = 40;          // 80B row stride (16B-aligned)
    static_assert(TILES % 4 == 0, "TILES % 4");

    __shared__ __align__(16) unsigned short sV[TWOJ * VROW];
    __shared__ __align__(16) unsigned short sA[128 * VROW];

    const int tid  = threadIdx.x;
    const int w    = tid >> 6;
    const int lane = tid & 63;
    const int l15  = lane & 15;
    const int q    = lane >> 4;
    const int n0   = blockIdx.x * 128;
    const int ng   = w & 1;             // node half (64 nodes)
    const int fg   = w >> 1;            // feature group
    const int tq   = fg * FT;

    f32x4 acc[FT][4];
    #pragma unroll
    for (int t = 0; t < FT; ++t)
        #pragma unroll
        for (int nt = 0; nt < 4; ++nt) acc[t][nt] = (f32x4){0.f, 0.f, 0.f, 0.f};

    for (int kc = 0; kc < CHUNKS; ++kc) {
        // ---- stage V chunk: straight bf16 copy, 16B units ----
        #pragma unroll
        for (int it = 0; it < TWOJ / 128; ++it) {
            int idx = it * 512 + tid;
            int row = idx >> 2;
            int seg = idx & 3;
            *(uint4*)(sV + row * VROW + seg * 8) =
                *(const uint4*)(Vg + (size_t)row * Kr + kc * 32 + seg * 8);
        }
        // ---- stage A chunk (128 nodes) ----
        if constexpr (REAL_IN) {
            const float* X = (const float*)Xv;
            #pragma unroll
            for (int it = 0; it < 2; ++it) {
                int idx = it * 512 + tid;
                int nl = idx >> 3;
                int cg = idx & 7;
                int n  = n0 + nl;
                float4 v = make_float4(0.f, 0.f, 0.f, 0.f);
                if (n < nNodes)
                    v = *(const float4*)(X + (size_t)n * Kr + kc * 32 + cg * 4);
                *(ushort4*)(sA + nl * VROW + cg * 4) =
                    make_ushort4(f2b(v.x), f2b(v.y), f2b(v.z), f2b(v.w));
            }
        } else {
            const unsigned short* X = (const unsigned short*)Xv;
            int nl  = tid >> 2;
            int seg = tid & 3;
            int n   = n0 + nl;
            uint4 v = make_uint4(0, 0, 0, 0);
            if (n < nNodes)
                v = *(const uint4*)(X + (size_t)n * Kr + kc * 32 + seg * 8);
            *(uint4*)(sA + nl * VROW + seg * 8) = v;
        }
        __syncthreads();

        // ---- inner: 4 bfrags (nodes) x FT afrags (features) ----
        bf16x8 bfrag[4];
        #pragma unroll
        for (int nt = 0; nt < 4; ++nt)
            bfrag[nt] = *(const bf16x8*)(sA + (ng * 64 + nt * 16 + l15) * VROW + q * 8);
        #pragma unroll
        for (int t = 0; t < FT; ++t) {
            bf16x8 afrag = *(const bf16x8*)(sV + ((tq + t) * 16 + l15) * VROW + q * 8);
            #pragma unroll
            for (int nt = 0; nt < 4; ++nt)
                acc[t][nt] = __builtin_amdgcn_mfma_f32_16x16x32_bf16(
                    afrag, bfrag[nt], acc[t][nt], 0, 0, 0);
        }
        __syncthreads();
    }

    // ---- epilogue ----
    float Fr = 1.f, Fi = 0.f, efr = 1.f, efi = 0.f;
    if constexpr (MIX) {
        float tr = trp[0], ti = tip[0];
        float er  = expf(ti);
        float tfr =  er * cosf(tr);
        float tfi = -er * sinf(tr);
        float eh  = expf(0.5f * ti);
        efr =  eh * cosf(0.5f * tr);
        efi = -eh * sinf(0.5f * tr);
        float omr = 1.f - efr, omi = -efi;
        Fr = tfr * omr - tfi * omi;
        Fi = tfr * omi + tfi * omr;
    }
    #pragma unroll
    for (int nt = 0; nt < 4; ++nt) {
        int n = n0 + ng * 64 + nt * 16 + l15;
        if (n >= nNodes) continue;
        float dg = 0.f;
        if constexpr (MIX) dg = (float)degp[n];
        #pragma unroll
        for (int t = 0; t < FT; ++t) {
            int f0 = (tq + t) * 16 + q * 4;
            int j0 = f0 >> 1;
            float re0, im0, re1, im1;
            if constexpr (MIX) {
                float ar0 = acc[t][nt][0] + dg * br[j0];
                float ai0 = acc[t][nt][1] + dg * bi[j0];
                float ar1 = acc[t][nt][2] + dg * br[j0 + 1];
                float ai1 = acc[t][nt][3] + dg * bi[j0 + 1];
                re0 = ar0 * Fr - ai0 * Fi;  im0 = ar0 * Fi + ai0 * Fr;
                re1 = ar1 * Fr - ai1 * Fi;  im1 = ar1 * Fi + ai1 * Fr;
                ushort4 hu = *(const ushort4*)(Hin + (size_t)n * TWOJ + f0);
                float hr0 = b2f(hu.x), hi0 = b2f(hu.y), hr1 = b2f(hu.z), hi1 = b2f(hu.w);
                re0 += hr0 * efr - hi0 * efi;  im0 += hr0 * efi + hi0 * efr;
                re1 += hr1 * efr - hi1 * efi;  im1 += hr1 * efi + hi1 * efr;
            } else {
                re0 = acc[t][nt][0] + br[j0];
                im0 = acc[t][nt][1] + bi[j0];
                re1 = acc[t][nt][2] + br[j0 + 1];
                im1 = acc[t][nt][3] + bi[j0 + 1];
                if constexpr (CRELU) {
                    re0 = fmaxf(re0, 0.f); im0 = fmaxf(im0, 0.f);
                    re1 = fmaxf(re1, 0.f); im1 = fmaxf(im1, 0.f);
                }
            }
            *(ushort4*)(Out + (size_t)n * TWOJ + f0) =
                make_ushort4(f2b(re0), f2b(im0), f2b(re1), f2b(im1));
        }
    }
}

// ---------------------------------------------------------------------------
// Bucket-CSR build (round 9): fixed 64-slot rows, single pass, XCD-partitioned.
// ---------------------------------------------------------------------------
#define EDGE_CHUNK 2048

__global__ __launch_bounds__(256) void build_kernel(
    const int* __restrict__ src, const int* __restrict__ dst,
    int* __restrict__ deg, int* __restrict__ csr, int E, int N)
{
    int x  = blockIdx.x & 7;
    int c  = blockIdx.x >> 3;
    int lo = (int)((long long)N * x / 8);
    int hi = (int)((long long)N * (x + 1) / 8);
    int base = c * EDGE_CHUNK;
    int end  = min(base + EDGE_CHUNK, E);
    for (int e = base + threadIdx.x; e < end; e += 256) {
        int d = dst[e];
        if (d >= lo && d < hi) {
            int s = src[e];
            if ((unsigned)s < (unsigned)N) {
                int pos = atomicAdd(&deg[d], 1);
                if (pos < 64) csr[((size_t)d << 6) + pos] = s;
            }
        }
    }
}

// ---------------------------------------------------------------------------
// Gather-sum over bucket rows (round 8/9 structure — at the L3 service floor).
// ---------------------------------------------------------------------------
template<int ROW>
__global__ __launch_bounds__(256) void gather_kernel(
    const unsigned short* __restrict__ h, unsigned short* __restrict__ agg,
    const int* __restrict__ deg, const int* __restrict__ csr, int N)
{
    constexpr int LPR = ROW / 8;
    constexpr int R   = 64 / LPR;
    int wid  = (blockIdx.x * 256 + threadIdx.x) >> 6;
    int lane = threadIdx.x & 63;
    if (wid >= N) return;
    const int subrow = lane / LPR;
    const int fofs   = (lane % LPR) * 8;
    int e   = wid << 6;
    int end = e + min(deg[wid], 64);

    float a[4][8];
    #pragma unroll
    for (int u = 0; u < 4; ++u)
        #pragma unroll
        for (int k = 0; k < 8; ++k) a[u][k] = 0.f;

    const unsigned short* hp = h + fofs;

    #define ACC_U4(bank, uu)                                                    \
        {                                                                       \
            a[bank][0] += __uint_as_float((uu).x << 16);                        \
            a[bank][1] += __uint_as_float((uu).x & 0xffff0000u);                \
            a[bank][2] += __uint_as_float((uu).y << 16);                        \
            a[bank][3] += __uint_as_float((uu).y & 0xffff0000u);                \
            a[bank][4] += __uint_as_float((uu).z << 16);                        \
            a[bank][5] += __uint_as_float((uu).z & 0xffff0000u);                \
            a[bank][6] += __uint_as_float((uu).w << 16);                        \
            a[bank][7] += __uint_as_float((uu).w & 0xffff0000u);                \
        }

    for (; e + 4 * R <= end; e += 4 * R) {
        int s0 = csr[e + 0 * R + subrow];
        int s1 = csr[e + 1 * R + subrow];
        int s2 = csr[e + 2 * R + subrow];
        int s3 = csr[e + 3 * R + subrow];
        uint4 u0 = *(const uint4*)(hp + (size_t)s0 * ROW);
        uint4 u1 = *(const uint4*)(hp + (size_t)s1 * ROW);
        uint4 u2 = *(const uint4*)(hp + (size_t)s2 * ROW);
        uint4 u3 = *(const uint4*)(hp + (size_t)s3 * ROW);
        ACC_U4(0, u0) ACC_U4(1, u1) ACC_U4(2, u2) ACC_U4(3, u3)
    }
    for (; e < end; e += R) {
        int idx = e + subrow;
        if (idx < end) {
            int s = csr[idx];
            uint4 u = *(const uint4*)(hp + (size_t)s * ROW);
            ACC_U4(0, u)
        }
    }
    #undef ACC_U4

    float r[8];
    #pragma unroll
    for (int k = 0; k < 8; ++k) {
        r[k] = a[0][k] + a[1][k] + a[2][k] + a[3][k];
        if (R >= 2) r[k] += __shfl_xor(r[k], 32, 64);
        if (R >= 4) r[k] += __shfl_xor(r[k], 16, 64);
    }
    if (subrow == 0) {
        unsigned short* op = agg + (size_t)wid * ROW + fofs;
        *(ushort4*)(op)     = make_ushort4(f2b(r[0]), f2b(r[1]), f2b(r[2]), f2b(r[3]));
        *(ushort4*)(op + 4) = make_ushort4(f2b(r[4]), f2b(r[5]), f2b(r[6]), f2b(r[7]));
    }
}

// ---------------------------------------------------------------------------
// abs + per-graph sum over final z [N,64]c bf16 (row = 128 ushorts).
// ---------------------------------------------------------------------------
__global__ __launch_bounds__(256) void abs_reduce_kernel(
    const unsigned short* __restrict__ z, const int* __restrict__ batch,
    float* __restrict__ sums, int N)
{
    constexpr int NPW = 16;
    int wid  = (blockIdx.x * 256 + threadIdx.x) >> 6;
    int lane = threadIdx.x & 63;
    int nBeg = wid * NPW;
    if (nBeg >= N) return;
    int nEnd = min(nBeg + NPW, N);

    float acc = 0.f;
    int cur_g = batch[nBeg];
    for (int n = nBeg; n < nEnd; ++n) {
        unsigned int u = *(const unsigned int*)(z + ((size_t)n << 7) + (lane << 1));
        float zr = b2f((unsigned short)(u & 0xffffu));
        float zi = b2f((unsigned short)(u >> 16));
        float a = sqrtf(zr * zr + zi * zi);
        int g = batch[n];
        if (g != cur_g) {
            if ((unsigned)cur_g < 64u) unsafeAtomicAdd(&sums[cur_g * 64 + lane], acc);
            acc = 0.f;
            cur_g = g;
        }
        acc += a;
    }
    if ((unsigned)cur_g < 64u) unsafeAtomicAdd(&sums[cur_g * 64 + lane], acc);
}

// per-graph count via binary search (batch sorted) + mean + log_softmax
__global__ __launch_bounds__(64) void finalize_kernel(
    const float* __restrict__ sums, const int* __restrict__ batch,
    float* __restrict__ out, int N)
{
    int g = blockIdx.x, d = threadIdx.x;
    __shared__ int cnt_s;
    if (d == 0) {
        int lo = 0, hi = N;
        while (lo < hi) { int mid = (lo + hi) >> 1; if (batch[mid] < g) lo = mid + 1; else hi = mid; }
        int lo2 = lo, hi2 = N;
        while (lo2 < hi2) { int mid = (lo2 + hi2) >> 1; if (batch[mid] < g + 1) lo2 = mid + 1; else hi2 = mid; }
        cnt_s = lo2 - lo;
    }
    __syncthreads();
    float c = fmaxf((float)cnt_s, 1.0f);
    float m = sums[g * 64 + d] / c;
    float mx = m;
    #pragma unroll
    for (int o = 32; o > 0; o >>= 1) mx = fmaxf(mx, __shfl_xor(mx, o, 64));
    float e = expf(m - mx);
    float s = e;
    #pragma unroll
    for (int o = 32; o > 0; o >>= 1) s += __shfl_xor(s, o, 64);
    out[g * 64 + d] = m - mx - logf(s);
}

extern "C" void kernel_launch(void* const* d_in, const int* in_sizes, int n_in,
                              void* d_out, int out_size, void* d_ws, size_t ws_size,
                              hipStream_t stream)
{
    const float* x   = (const float*)d_in[0];
    const float* W0r = (const float*)d_in[1];
    const float* W0i = (const float*)d_in[2];
    const float* b0r = (const float*)d_in[3];
    const float* b0i = (const float*)d_in[4];
    const float* M0r = (const float*)d_in[5];
    const float* M0i = (const float*)d_in[6];
    const float* c0r = (const float*)d_in[7];
    const float* c0i = (const float*)d_in[8];
    const float* t0r = (const float*)d_in[9];
    const float* t0i = (const float*)d_in[10];
    const float* W1r = (const float*)d_in[11];
    const float* W1i = (const float*)d_in[12];
    const float* b1r = (const float*)d_in[13];
    const float* b1i = (const float*)d_in[14];
    const float* M1r = (const float*)d_in[15];
    const float* M1i = (const float*)d_in[16];
    const float* c1r = (const float*)d_in[17];
    const float* c1i = (const float*)d_in[18];
    const float* t1r = (const float*)d_in[19];
    const float* t1i = (const float*)d_in[20];
    const int* edge  = (const int*)d_in[21];
    const int* batch = (const int*)d_in[22];

    const int N = in_sizes[0] / 128;
    const int E = in_sizes[21] / 2;
    const int* src = edge;
    const int* dst = edge + E;

    // ---- workspace (~180 MB) ----
    unsigned short* h0   = (unsigned short*)d_ws;       // becomes x1, in place
    unsigned short* aggA = h0 + (size_t)N * 256;
    unsigned short* h1   = aggA + (size_t)N * 256;      // becomes z, in place
    unsigned short* aggB = h1 + (size_t)N * 128;
    int*   deg  = (int*)(aggB + (size_t)N * 128);
    int*   csr  = deg + N;
    float* sums = (float*)(csr + (size_t)N * 64);
    unsigned short* V0  = (unsigned short*)(sums + 4096);  // [256,128]
    unsigned short* VM0 = V0  + 256 * 128;                 // [256,256]
    unsigned short* V1  = VM0 + 256 * 256;                 // [128,256]
    unsigned short* VM1 = V1  + 128 * 256;                 // [128,128]

    const int gemmGrid = (N + 127) / 128;
    const int xcdEdgeGrid = ((E + EDGE_CHUNK - 1) / EDGE_CHUNK) * 8;
    const int waveGrid = (N * 64 + 255) / 256;
    const int wave16Grid = ((N + 15) / 16 * 64 + 255) / 256;

    // ---- fused prep (V matrices + deg/sums zero) + bucket-CSR build ----
    prep_all_kernel<<<176, 256, 0, stream>>>(
        W0r, W0i, M0r, M0i, W1r, W1i, M1r, M1i,
        V0, VM0, V1, VM1, deg, sums, N);
    build_kernel<<<xcdEdgeGrid, 256, 0, stream>>>(src, dst, deg, csr, E, N);

    // ---- layer 0 ----
    mfma_cgemm_kernel<128,256,true,true,false><<<gemmGrid, 512, 0, stream>>>(
        x, V0, b0r, b0i, nullptr, nullptr, nullptr, nullptr, h0, N);
    gather_kernel<256><<<waveGrid, 256, 0, stream>>>(h0, aggA, deg, csr, N);
    mfma_cgemm_kernel<256,256,false,false,true><<<gemmGrid, 512, 0, stream>>>(
        aggA, VM0, c0r, c0i, t0r, t0i, h0, deg, h0, N);

    // ---- layer 1 ----
    mfma_cgemm_kernel<256,128,false,true,false><<<gemmGrid, 512, 0, stream>>>(
        h0, V1, b1r, b1i, nullptr, nullptr, nullptr, nullptr, h1, N);
    gather_kernel<128><<<waveGrid, 256, 0, stream>>>(h1, aggB, deg, csr, N);
    mfma_cgemm_kernel<128,128,false,false,true><<<gemmGrid, 512, 0, stream>>>(
        aggB, VM1, c1r, c1i, t1r, t1i, h1, deg, h1, N);

    // ---- readout ----
    abs_reduce_kernel<<<wave16Grid, 256, 0, stream>>>(h1, batch, sums, N);
    finalize_kernel<<<64, 64, 0, stream>>>(sums, batch, (float*)d_out, N);
}